// Round 1
// baseline (333.577 us; speedup 1.0000x reference)
//
#include <hip/hip_runtime.h>

// Causal flash attention, B=4 H=16 S=2048 D=64, fp32 in/out, bf16 MFMA compute.
// Structure: 4 waves/block, each wave owns 16 q-rows (block = 64 q-rows).
// Key loop over 64-key tiles: stage K (row-major) + V (transposed) as bf16 in
// LDS with chunk-rotation swizzle; QK^T via mfma_f32_16x16x32_bf16; online
// softmax on C-layout frags; P round-trips through LDS into A-layout; PV MFMA.

#define S_LEN 2048
#define D_HEAD 64
#define NBH 64      // B*H
#define QBLK 32     // S / 64

typedef float f32x4 __attribute__((ext_vector_type(4)));
typedef short s16x8 __attribute__((ext_vector_type(8)));

#define SCLOG2E (0.125f * 1.44269504088896340736f)  // 1/sqrt(D) * log2(e)

__device__ __forceinline__ unsigned short f2bf(float x) {
    union { float f; unsigned int u; } v; v.f = x;
    unsigned int u = v.u + 0x7FFFu + ((v.u >> 16) & 1u);  // RNE
    return (unsigned short)(u >> 16);
}

// rotation swizzle: element (row, col) of a 64-wide bf16 row lives at
// row*64 + phys_chunk*8 + (col&7), phys_chunk = ((col>>3) + row) & 7.
// Keeps 16B frag reads (all lanes same chunk-index, different rows)
// bandwidth-optimal instead of 16-way conflicted.
__device__ __forceinline__ int swz(int row, int col) {
    return row * 64 + ((((col >> 3) + row) & 7) << 3) + (col & 7);
}

__global__ __launch_bounds__(256, 2)
void fattn_kernel(const float* __restrict__ Qg, const float* __restrict__ Kg,
                  const float* __restrict__ Vg, float* __restrict__ Og)
{
    __shared__ __align__(16) unsigned short ks[64 * 64];       // K tile, row-major [key][d]
    __shared__ __align__(16) unsigned short vs[64 * 64];       // V tile, transposed [d][key]
    __shared__ __align__(16) unsigned short ps[4 * 16 * 64];   // P per wave, [qrow][key]

    const int bx = blockIdx.x;
    const int bh = bx & (NBH - 1);   // fast-varying: equal-work concurrent blocks
    const int qb = bx >> 6;
    const size_t base = (size_t)bh * (S_LEN * D_HEAD);
    const float* q = Qg + base;
    const float* k = Kg + base;
    const float* v = Vg + base;
    float*       o = Og + base;

    const int t    = threadIdx.x;
    const int w    = t >> 6;
    const int lane = t & 63;
    const int col  = lane & 15;
    const int quad = lane >> 4;

    // ---- Q fragments, A-layout: lane holds Q[w*16 + (lane&15)][quad*8 + j + 32*kt]
    s16x8 qa[2];
    {
        const int qr = qb * 64 + w * 16 + col;
        const float* p0 = q + (size_t)qr * D_HEAD + quad * 8;
#pragma unroll
        for (int kt = 0; kt < 2; ++kt) {
            const float* p = p0 + kt * 32;
            float4 x = *(const float4*)(p);
            float4 y = *(const float4*)(p + 4);
            s16x8 f;
            f[0] = (short)f2bf(x.x); f[1] = (short)f2bf(x.y);
            f[2] = (short)f2bf(x.z); f[3] = (short)f2bf(x.w);
            f[4] = (short)f2bf(y.x); f[5] = (short)f2bf(y.y);
            f[6] = (short)f2bf(y.z); f[7] = (short)f2bf(y.w);
            qa[kt] = f;
        }
    }

    float m_r[4], l_r[4];
    f32x4 oacc[4];
#pragma unroll
    for (int r = 0; r < 4; ++r) { m_r[r] = -__builtin_inff(); l_r[r] = 0.f; }
#pragma unroll
    for (int nt = 0; nt < 4; ++nt) oacc[nt] = (f32x4){0.f, 0.f, 0.f, 0.f};

    for (int j = 0; j <= qb; ++j) {
        __syncthreads();   // protect ks/vs reuse across iterations
        const int kb = j * 64;

        // ---- stage K tile (row-major bf16, swizzled): 512 16B-chunks, 2/thread
#pragma unroll
        for (int i = 0; i < 2; ++i) {
            int chunk = t + 256 * i;
            int row = chunk >> 3, c = chunk & 7;
            const float* p = k + (size_t)(kb + row) * D_HEAD + c * 8;
            float4 x = *(const float4*)p;
            float4 y = *(const float4*)(p + 4);
            s16x8 f;
            f[0] = (short)f2bf(x.x); f[1] = (short)f2bf(x.y);
            f[2] = (short)f2bf(x.z); f[3] = (short)f2bf(x.w);
            f[4] = (short)f2bf(y.x); f[5] = (short)f2bf(y.y);
            f[6] = (short)f2bf(y.z); f[7] = (short)f2bf(y.w);
            *(s16x8*)&ks[swz(row, c * 8)] = f;
        }
        // ---- stage V tile transposed ([d][key], swizzled); scalar writes are
        // 2-way conflict-free with this thread->element mapping.
        {
            int key = t & 63, cc = t >> 6;
#pragma unroll
            for (int ci = 0; ci < 2; ++ci) {
                int c = cc + ci * 4;
                const float* p = v + (size_t)(kb + key) * D_HEAD + c * 8;
                float4 x = *(const float4*)p;
                float4 y = *(const float4*)(p + 4);
                float vals[8] = {x.x, x.y, x.z, x.w, y.x, y.y, y.z, y.w};
#pragma unroll
                for (int jj = 0; jj < 8; ++jj) {
                    int d = c * 8 + jj;
                    vs[swz(d, key)] = f2bf(vals[jj]);
                }
            }
        }
        __syncthreads();

        // ---- S = Q K^T  (4 key n-tiles x 2 d k-tiles)
        f32x4 sf[4];
#pragma unroll
        for (int nt = 0; nt < 4; ++nt) sf[nt] = (f32x4){0.f, 0.f, 0.f, 0.f};
#pragma unroll
        for (int kt = 0; kt < 2; ++kt) {
#pragma unroll
            for (int nt = 0; nt < 4; ++nt) {
                int key = nt * 16 + col;
                s16x8 bf = *(const s16x8*)&ks[swz(key, (4 * kt + quad) * 8)];
                sf[nt] = __builtin_amdgcn_mfma_f32_16x16x32_bf16(qa[kt], bf, sf[nt], 0, 0, 0);
            }
        }

        // ---- scale (+ causal mask on the diagonal tile)
        if (j == qb) {
#pragma unroll
            for (int nt = 0; nt < 4; ++nt)
#pragma unroll
                for (int r = 0; r < 4; ++r) {
                    int keyl = nt * 16 + col;
                    int qrl  = w * 16 + quad * 4 + r;
                    sf[nt][r] = (keyl > qrl) ? -__builtin_inff() : sf[nt][r] * SCLOG2E;
                }
        } else {
#pragma unroll
            for (int nt = 0; nt < 4; ++nt)
#pragma unroll
                for (int r = 0; r < 4; ++r) sf[nt][r] *= SCLOG2E;
        }

        // ---- online softmax; row r's 16 key-cols live in this quad's 16 lanes
        float pb[4][4];  // [nt][r]
#pragma unroll
        for (int r = 0; r < 4; ++r) {
            float mx = fmaxf(fmaxf(sf[0][r], sf[1][r]), fmaxf(sf[2][r], sf[3][r]));
            mx = fmaxf(mx, __shfl_xor(mx, 1));
            mx = fmaxf(mx, __shfl_xor(mx, 2));
            mx = fmaxf(mx, __shfl_xor(mx, 4));
            mx = fmaxf(mx, __shfl_xor(mx, 8));
            float mnew  = fmaxf(m_r[r], mx);
            float alpha = exp2f(m_r[r] - mnew);   // first iter: exp2(-inf)=0
            m_r[r] = mnew;
            float rs = 0.f;
#pragma unroll
            for (int nt = 0; nt < 4; ++nt) {
                float p = exp2f(sf[nt][r] - mnew);
                pb[nt][r] = p;
                rs += p;
            }
            rs += __shfl_xor(rs, 1);
            rs += __shfl_xor(rs, 2);
            rs += __shfl_xor(rs, 4);
            rs += __shfl_xor(rs, 8);
            l_r[r] = l_r[r] * alpha + rs;
#pragma unroll
            for (int nt = 0; nt < 4; ++nt) oacc[nt][r] *= alpha;
        }

        // ---- P -> LDS (C-layout -> row-major [qrow][key], per-wave region)
#pragma unroll
        for (int nt = 0; nt < 4; ++nt)
#pragma unroll
            for (int r = 0; r < 4; ++r) {
                int qrl = quad * 4 + r;
                int key = nt * 16 + col;
                ps[w * 1024 + swz(qrl, key)] = f2bf(pb[nt][r]);
            }
        __syncthreads();   // order P writes before A-frag reads (conservative)

        // ---- O += P V   (A = P from LDS in A-layout, B = V^T-staged tile)
#pragma unroll
        for (int kt = 0; kt < 2; ++kt) {
            s16x8 af = *(const s16x8*)&ps[w * 1024 + swz(col, (4 * kt + quad) * 8)];
#pragma unroll
            for (int nt = 0; nt < 4; ++nt) {
                int d = nt * 16 + col;
                s16x8 bf = *(const s16x8*)&vs[swz(d, (4 * kt + quad) * 8)];
                oacc[nt] = __builtin_amdgcn_mfma_f32_16x16x32_bf16(af, bf, oacc[nt], 0, 0, 0);
            }
        }
    }

    // ---- epilogue: O / l, fp32 store (C-layout: row=quad*4+r, col=lane&15)
#pragma unroll
    for (int r = 0; r < 4; ++r) {
        float inv = 1.f / l_r[r];
        int row = qb * 64 + w * 16 + quad * 4 + r;
        float* po = o + (size_t)row * D_HEAD;
#pragma unroll
        for (int nt = 0; nt < 4; ++nt) po[nt * 16 + col] = oacc[nt][r] * inv;
    }
}

extern "C" void kernel_launch(void* const* d_in, const int* in_sizes, int n_in,
                              void* d_out, int out_size, void* d_ws, size_t ws_size,
                              hipStream_t stream) {
    const float* q = (const float*)d_in[0];
    const float* k = (const float*)d_in[1];
    const float* v = (const float*)d_in[2];
    // d_in[3] is the causal tril mask — applied analytically in-kernel.
    float* out = (float*)d_out;
    dim3 grid(NBH * QBLK);  // 2048 workgroups
    fattn_kernel<<<grid, dim3(256), 0, stream>>>(q, k, v, out);
}

// Round 2
// 213.124 us; speedup vs baseline: 1.5652x; 1.5652x over previous
//
#include <hip/hip_runtime.h>

// Causal flash attention, B=4 H=16 S=2048 D=64, fp32 in/out, bf16 MFMA.
// R2: pre-convert K/V to bf16 swizzled tile images in d_ws (pre-pass kernel),
// main kernel stages via global_load_lds width=16 (no VALU conversion),
// double-buffered K/V (1 barrier/tile), no-running-max softmax with row sums
// via ones-MFMA, heavy-first block order. Fallback (in-kernel convert) if
// ws_size < 32 MB.

#define S_LEN 2048
#define D_HEAD 64
#define NBH 64      // B*H
#define QBLK 32     // S / 64
#define TILE_E 4096 // 64x64 elements per k-tile image

typedef float f32x4 __attribute__((ext_vector_type(4)));
typedef short s16x8 __attribute__((ext_vector_type(8)));

#define SCLOG2E (0.125f * 1.44269504088896340736f)  // 1/sqrt(D) * log2(e)

__device__ __forceinline__ unsigned short f2bf(float x) {  // RNE (pre-pass)
    union { float f; unsigned int u; } v; v.f = x;
    unsigned int u = v.u + 0x7FFFu + ((v.u >> 16) & 1u);
    return (unsigned short)(u >> 16);
}
__device__ __forceinline__ unsigned short f2bf_hu(float x) { // half-up (P path)
    union { float f; unsigned int u; } v; v.f = x;
    return (unsigned short)((v.u + 0x8000u) >> 16);
}

// chunk-rotation swizzle (R1-verified: 0 bank conflicts)
__device__ __forceinline__ int swz(int row, int col) {
    return row * 64 + ((((col >> 3) + row) & 7) << 3) + (col & 7);
}

// async global->LDS, 16B per lane; lds dst must be wave-uniform base (lane*16 auto)
__device__ __forceinline__ void g2l(const unsigned short* g, unsigned short* l) {
    __builtin_amdgcn_global_load_lds(
        (const __attribute__((address_space(1))) void*)g,
        (__attribute__((address_space(3))) void*)l, 16, 0, 0);
}

// ---------- pre-pass: fp32 K,V -> bf16 swizzled tile images in workspace ----
__global__ __launch_bounds__(256)
void preconv_kernel(const float* __restrict__ K, const float* __restrict__ V,
                    unsigned short* __restrict__ Kw, unsigned short* __restrict__ Vw)
{
    __shared__ __align__(16) unsigned short kt[TILE_E];
    __shared__ __align__(16) unsigned short vt[TILE_E];
    const int bh = blockIdx.x & (NBH - 1);
    const int j  = blockIdx.x >> 6;
    const float* k = K + (size_t)bh * (S_LEN * D_HEAD) + (size_t)j * 64 * D_HEAD;
    const float* v = V + (size_t)bh * (S_LEN * D_HEAD) + (size_t)j * 64 * D_HEAD;
    const int t = threadIdx.x;

    // K tile, row-major [key][d], swizzled
#pragma unroll
    for (int i = 0; i < 2; ++i) {
        int chunk = t + 256 * i;
        int row = chunk >> 3, c = chunk & 7;
        const float* p = k + (size_t)row * D_HEAD + c * 8;
        float4 x = *(const float4*)p;
        float4 y = *(const float4*)(p + 4);
        s16x8 f;
        f[0] = (short)f2bf(x.x); f[1] = (short)f2bf(x.y);
        f[2] = (short)f2bf(x.z); f[3] = (short)f2bf(x.w);
        f[4] = (short)f2bf(y.x); f[5] = (short)f2bf(y.y);
        f[6] = (short)f2bf(y.z); f[7] = (short)f2bf(y.w);
        *(s16x8*)&kt[swz(row, c * 8)] = f;
    }
    // V tile, transposed [d][key], swizzled
    {
        int key = t & 63, cc = t >> 6;
#pragma unroll
        for (int ci = 0; ci < 2; ++ci) {
            int c = cc + ci * 4;
            const float* p = v + (size_t)key * D_HEAD + c * 8;
            float4 x = *(const float4*)p;
            float4 y = *(const float4*)(p + 4);
            float vals[8] = {x.x, x.y, x.z, x.w, y.x, y.y, y.z, y.w};
#pragma unroll
            for (int jj = 0; jj < 8; ++jj)
                vt[swz(c * 8 + jj, key)] = f2bf(vals[jj]);
        }
    }
    __syncthreads();
    // dump LDS images verbatim, coalesced
    const size_t tb = (size_t)(bh * QBLK + j) * TILE_E;
#pragma unroll
    for (int i = 0; i < 2; ++i) {
        int idx = (t + 256 * i) * 8;
        *(s16x8*)&Kw[tb + idx] = *(const s16x8*)&kt[idx];
        *(s16x8*)&Vw[tb + idx] = *(const s16x8*)&vt[idx];
    }
}

// ---------------------------- main kernel -----------------------------------
template <bool PRE>
__global__ __launch_bounds__(256, 2)
void fattn_kernel(const float* __restrict__ Qg, const float* __restrict__ Kg,
                  const float* __restrict__ Vg, float* __restrict__ Og,
                  const unsigned short* __restrict__ Kw,
                  const unsigned short* __restrict__ Vw)
{
    __shared__ __align__(16) unsigned short ks[2][TILE_E];
    __shared__ __align__(16) unsigned short vs[2][TILE_E];
    __shared__ __align__(16) unsigned short ps[4][1024];

    const int bx = blockIdx.x;
    const int bh = bx & (NBH - 1);
    const int qb = (QBLK - 1) - (bx >> 6);   // heavy blocks dispatched first
    const size_t base = (size_t)bh * (S_LEN * D_HEAD);
    const float* q = Qg + base;
    const float* k = Kg + base;
    const float* v = Vg + base;
    float*       o = Og + base;

    const int t    = threadIdx.x;
    const int w    = t >> 6;
    const int lane = t & 63;
    const int col  = lane & 15;
    const int quad = lane >> 4;

    // Q fragments (A-layout), fp32->bf16 once per block
    s16x8 qa[2];
    {
        const int qr = qb * 64 + w * 16 + col;
        const float* p0 = q + (size_t)qr * D_HEAD + quad * 8;
#pragma unroll
        for (int kt2 = 0; kt2 < 2; ++kt2) {
            const float* p = p0 + kt2 * 32;
            float4 x = *(const float4*)(p);
            float4 y = *(const float4*)(p + 4);
            s16x8 f;
            f[0] = (short)f2bf(x.x); f[1] = (short)f2bf(x.y);
            f[2] = (short)f2bf(x.z); f[3] = (short)f2bf(x.w);
            f[4] = (short)f2bf(y.x); f[5] = (short)f2bf(y.y);
            f[6] = (short)f2bf(y.z); f[7] = (short)f2bf(y.w);
            qa[kt2] = f;
        }
    }

    s16x8 ones;
#pragma unroll
    for (int i = 0; i < 8; ++i) ones[i] = (short)0x3F80;  // bf16 1.0

    f32x4 oacc[4], lf;
#pragma unroll
    for (int nt = 0; nt < 4; ++nt) oacc[nt] = (f32x4){0.f, 0.f, 0.f, 0.f};
    lf = (f32x4){0.f, 0.f, 0.f, 0.f};

    auto stage = [&](int jt, int buf) {
        if constexpr (PRE) {
            const size_t tb = (size_t)(bh * QBLK + jt) * TILE_E;
#pragma unroll
            for (int i = 0; i < 2; ++i) {
                int c = w * 2 + i;             // 8 chunks of 512 elem (1 KiB)
                g2l(Kw + tb + c * 512 + lane * 8, &ks[buf][c * 512]);
                g2l(Vw + tb + c * 512 + lane * 8, &vs[buf][c * 512]);
            }
        } else {
            const int kb = jt * 64;
#pragma unroll
            for (int i = 0; i < 2; ++i) {
                int chunk = t + 256 * i;
                int row = chunk >> 3, c = chunk & 7;
                const float* p = k + (size_t)(kb + row) * D_HEAD + c * 8;
                float4 x = *(const float4*)p;
                float4 y = *(const float4*)(p + 4);
                s16x8 f;
                f[0] = (short)f2bf(x.x); f[1] = (short)f2bf(x.y);
                f[2] = (short)f2bf(x.z); f[3] = (short)f2bf(x.w);
                f[4] = (short)f2bf(y.x); f[5] = (short)f2bf(y.y);
                f[6] = (short)f2bf(y.z); f[7] = (short)f2bf(y.w);
                *(s16x8*)&ks[buf][swz(row, c * 8)] = f;
            }
            int key = t & 63, cc = t >> 6;
#pragma unroll
            for (int ci = 0; ci < 2; ++ci) {
                int c = cc + ci * 4;
                const float* p = v + (size_t)(kb + key) * D_HEAD + c * 8;
                float4 x = *(const float4*)p;
                float4 y = *(const float4*)(p + 4);
                float vals[8] = {x.x, x.y, x.z, x.w, y.x, y.y, y.z, y.w};
#pragma unroll
                for (int jj = 0; jj < 8; ++jj)
                    vs[buf][swz(c * 8 + jj, key)] = f2bf(vals[jj]);
            }
        }
    };

    stage(0, 0);

    for (int j = 0; j <= qb; ++j) {
        const int cur = j & 1;
        __syncthreads();                 // drains prefetch DMA (vmcnt) + guards reuse
        if (j < qb) stage(j + 1, 1 - cur);

        // ---- S = Q K^T
        f32x4 sf[4];
#pragma unroll
        for (int nt = 0; nt < 4; ++nt) sf[nt] = (f32x4){0.f, 0.f, 0.f, 0.f};
#pragma unroll
        for (int kt2 = 0; kt2 < 2; ++kt2) {
#pragma unroll
            for (int nt = 0; nt < 4; ++nt) {
                int key = nt * 16 + col;
                s16x8 bf = *(const s16x8*)&ks[cur][swz(key, (4 * kt2 + quad) * 8)];
                sf[nt] = __builtin_amdgcn_mfma_f32_16x16x32_bf16(qa[kt2], bf, sf[nt], 0, 0, 0);
            }
        }

        // ---- scale (+ causal mask on diagonal tile), exp2, P -> LDS
        if (j == qb) {
#pragma unroll
            for (int nt = 0; nt < 4; ++nt)
#pragma unroll
                for (int r = 0; r < 4; ++r) {
                    int keyl = nt * 16 + col;
                    int qrl  = w * 16 + quad * 4 + r;
                    sf[nt][r] = (keyl > qrl) ? -__builtin_inff() : sf[nt][r] * SCLOG2E;
                }
        } else {
#pragma unroll
            for (int nt = 0; nt < 4; ++nt)
#pragma unroll
                for (int r = 0; r < 4; ++r) sf[nt][r] *= SCLOG2E;
        }
#pragma unroll
        for (int nt = 0; nt < 4; ++nt)
#pragma unroll
            for (int r = 0; r < 4; ++r) {
                int qrl = quad * 4 + r;
                int key = nt * 16 + col;
                ps[w][swz(qrl, key)] = f2bf_hu(exp2f(sf[nt][r]));
            }
        // per-wave LDS region; in-wave DS ordering — no barrier needed

        // ---- O += P V ; l += P * ones  (row sums free via MFMA)
#pragma unroll
        for (int kt2 = 0; kt2 < 2; ++kt2) {
            s16x8 af = *(const s16x8*)&ps[w][swz(col, (4 * kt2 + quad) * 8)];
            lf = __builtin_amdgcn_mfma_f32_16x16x32_bf16(af, ones, lf, 0, 0, 0);
#pragma unroll
            for (int nt = 0; nt < 4; ++nt) {
                int d = nt * 16 + col;
                s16x8 bf = *(const s16x8*)&vs[cur][swz(d, (4 * kt2 + quad) * 8)];
                oacc[nt] = __builtin_amdgcn_mfma_f32_16x16x32_bf16(af, bf, oacc[nt], 0, 0, 0);
            }
        }
    }

    // ---- epilogue
#pragma unroll
    for (int r = 0; r < 4; ++r) {
        float inv = 1.f / lf[r];
        int row = qb * 64 + w * 16 + quad * 4 + r;
        float* po = o + (size_t)row * D_HEAD;
#pragma unroll
        for (int nt = 0; nt < 4; ++nt) po[nt * 16 + col] = oacc[nt][r] * inv;
    }
}

extern "C" void kernel_launch(void* const* d_in, const int* in_sizes, int n_in,
                              void* d_out, int out_size, void* d_ws, size_t ws_size,
                              hipStream_t stream) {
    const float* q = (const float*)d_in[0];
    const float* k = (const float*)d_in[1];
    const float* v = (const float*)d_in[2];
    float* out = (float*)d_out;

    const size_t kv_elems = (size_t)NBH * QBLK * TILE_E;   // 8M elems = 16 MB each
    if (ws_size >= 2 * kv_elems * sizeof(unsigned short)) {
        unsigned short* Kw = (unsigned short*)d_ws;
        unsigned short* Vw = Kw + kv_elems;
        preconv_kernel<<<dim3(NBH * QBLK), dim3(256), 0, stream>>>(k, v, Kw, Vw);
        fattn_kernel<true><<<dim3(NBH * QBLK), dim3(256), 0, stream>>>(q, k, v, out, Kw, Vw);
    } else {
        fattn_kernel<false><<<dim3(NBH * QBLK), dim3(256), 0, stream>>>(q, k, v, out, nullptr, nullptr);
    }
}